// Round 8
// baseline (746.909 us; speedup 1.0000x reference)
//
#include <hip/hip_runtime.h>
#include <hip/hip_bf16.h>

typedef __attribute__((ext_vector_type(8))) short bf16x8;
typedef __attribute__((ext_vector_type(4))) float f32x4;

#define GLD16(g, s) __builtin_amdgcn_global_load_lds( \
    (const __attribute__((address_space(1))) void*)(g), \
    (__attribute__((address_space(3))) void*)(s), 16, 0, 0)

#define SBAR() __builtin_amdgcn_sched_barrier(0)
#define BARRIER() __builtin_amdgcn_s_barrier()
#define WAIT_LGKM0() do { asm volatile("s_waitcnt lgkmcnt(0)" ::: "memory"); SBAR(); } while (0)
#define WAIT_VM(n) do { asm volatile("s_waitcnt vmcnt(" #n ")" ::: "memory"); SBAR(); } while (0)

static constexpr int kB  = 128;
static constexpr int kC  = 1280;
static constexpr int kHW = 256;

// Counted-vmcnt phased GEMM: C(M,N) = A(M,K)*Bt(N,K)^T.
// BM=BN=256, BK=64; 512 thr = 8 waves (2M x 4N), wave tile 128x64,
// MFMA 16x16x32 (conflict-free under (row&7)<<4 swizzle; measured R2-R5/R7).
// 2 LDS slots x 64KB. Tile t+1's 8 loads issued at tile-t boundary (into the
// slot whose readers all retired via lgkmcnt(0)+barrier); main-loop waits are
// vmcnt(10)/vmcnt(8) ONLY (T4) -- issue->wait distance = a full K-tile.
// Stage order pb[0..3],pa[0],pa[2],pa[1],pa[3] makes "oldest 6" = ph0's needs.
// OUT_MODE: 0=bf16 rowmajor, 1=f32 rowmajor, 2=bf16 conv, 3=f32 conv alpha*()+resid
// BIAS_MODE: 0=none, 1=bias[col], 2=bias[row]
// ORDER: 0 = m-fastest (B operand large), 1 = n-fastest (A operand large)
template<int OUT_MODE, int BIAS_MODE, int ORDER>
__global__ __launch_bounds__(512, 2) void gemm_t(
    const __hip_bfloat16* __restrict__ A,
    const __hip_bfloat16* __restrict__ Bt,
    void* __restrict__ outp,
    const float* __restrict__ bias,
    const float* __restrict__ resid,
    const float* __restrict__ alphap,
    int M, int N, int K,
    int ldA, int ldB, long sA, long sB, long sC, int ldC)
{
    extern __shared__ char smem[];   // 2 slots x 65536 (A 32K + B 32K each)
    const int t = threadIdx.x;
    const int w = t >> 6, l = t & 63;
    const int q = l >> 4, r16 = l & 15;
    const int wr = w >> 2, wc = w & 3;   // 2M x 4N waves
    const int z = blockIdx.z;
    const int nbm = M >> 8, nbn = N >> 8;
    const int nwg = nbm * nbn;
    int f = blockIdx.x;
    {   // bijective XCD swizzle (m204)
        const int q8 = nwg >> 3, r8 = nwg & 7;
        const int xcd = f & 7, rank = f >> 3;
        f = (xcd < r8 ? xcd * (q8 + 1) : r8 * (q8 + 1) + (xcd - r8) * q8) + rank;
    }
    long m0, n0;
    if (ORDER == 0) { m0 = (long)(f % nbm) << 8; n0 = (long)(f / nbm) << 8; }
    else            { n0 = (long)(f % nbn) << 8; m0 = (long)(f / nbn) << 8; }
    const char* Azb = (const char*)(A + (long)z * sA);
    const char* Bzb = (const char*)(Bt + (long)z * sB);

    // ---- hoisted staging addresses (advance +128B per K-tile) ----
    const char* pa[4];
    const char* pb[4];
    int ldsd[4];
    #pragma unroll
    for (int i = 0; i < 4; ++i) {
        const int d = i * 8192 + t * 16;
        const int row = d >> 7;
        const int cb = (d & 127) ^ ((row & 7) << 4);   // inverse-swizzled source
        pa[i] = Azb + ((m0 + row) * (long)ldA) * 2 + cb;
        pb[i] = Bzb + ((n0 + row) * (long)ldB) * 2 + cb;
        ldsd[i] = d;
    }
    // issue order: pb0,pb1,pb2,pb3, pa0,pa2, pa1,pa3
    // -> oldest-6 = full B + A row-half0 (exactly what ph0 reads)
    auto stage8 = [&](char* base) {
        GLD16(pb[0], base + 32768 + ldsd[0]);
        GLD16(pb[1], base + 32768 + ldsd[1]);
        GLD16(pb[2], base + 32768 + ldsd[2]);
        GLD16(pb[3], base + 32768 + ldsd[3]);
        GLD16(pa[0], base + ldsd[0]);
        GLD16(pa[2], base + ldsd[2]);
        GLD16(pa[1], base + ldsd[1]);
        GLD16(pa[3], base + ldsd[3]);
        #pragma unroll
        for (int i = 0; i < 4; ++i) { pa[i] += 128; pb[i] += 128; }
    };

    // ---- hoisted LDS read constants ----
    // frag addr(mi,kk) = slot + (wrbase + mi*16 + r16)*128 + (cx ^ (kk<<6))
    const int cx  = (q << 4) ^ ((l & 7) << 4);
    const int cK0 = cx, cK1 = cx ^ 64;
    const int arow = (wr * 128 + r16) * 128;           // + mih*8192 + j*2048
    const int brow = 32768 + (wc * 64 + r16) * 128;    // + ni*2048

#define DSA(dst, sb, mih, ckk) do { const char* p_ = (sb) + arow + (ckk) + (mih) * 8192; \
    dst[0] = *(const bf16x8*)(p_);        dst[1] = *(const bf16x8*)(p_ + 2048); \
    dst[2] = *(const bf16x8*)(p_ + 4096); dst[3] = *(const bf16x8*)(p_ + 6144); } while (0)
#define DSB(dst, sb, ckk) do { const char* p_ = (sb) + brow + (ckk); \
    dst[0] = *(const bf16x8*)(p_);        dst[1] = *(const bf16x8*)(p_ + 2048); \
    dst[2] = *(const bf16x8*)(p_ + 4096); dst[3] = *(const bf16x8*)(p_ + 6144); } while (0)
#define MM16(ar, br, mih) do { __builtin_amdgcn_s_setprio(1); \
    _Pragma("unroll") for (int j = 0; j < 4; ++j) \
    _Pragma("unroll") for (int ni = 0; ni < 4; ++ni) \
        acc[(mih) * 4 + j][ni] = __builtin_amdgcn_mfma_f32_16x16x32_bf16( \
            ar[j], br[ni], acc[(mih) * 4 + j][ni], 0, 0, 0); \
    __builtin_amdgcn_s_setprio(0); SBAR(); } while (0)

    f32x4 acc[8][4] = {};
    const int nK = K >> 6;

    stage8(smem);                      // tile 0 -> slot 0

    for (int tk = 0; tk < nK; ++tk) {
        char* sb = smem + (tk & 1) * 65536;
        char* nb = smem + ((tk & 1) ^ 1) * 65536;
        const bool stg = (tk + 1 < nK);

        // boundary: slot nb's readers all retired (lgkm0+barrier last tile);
        // issue tile t+1 into it, then wait only for tile t's oldest 6.
        if (stg) { stage8(nb); WAIT_VM(10); }
        else     { WAIT_VM(2); }
        BARRIER(); SBAR();

        bf16x8 a0[4], a1[4], b0[4], b1[4];

        // ---- phase 0: kk0, mi 0-3 ----
        DSB(b0, sb, cK0);
        DSA(a0, sb, 0, cK0);
        SBAR(); BARRIER(); WAIT_LGKM0();
        MM16(a0, b0, 0);
        if (stg) WAIT_VM(8); else WAIT_VM(0);   // tile t's pa1,pa3 landed
        BARRIER(); SBAR();

        // ---- phase 1: kk0, mi 4-7 ----
        DSA(a1, sb, 1, cK0);
        SBAR(); BARRIER(); WAIT_LGKM0();
        MM16(a1, b0, 1);
        BARRIER(); SBAR();

        // ---- phase 2: kk1, mi 0-3 ----
        DSB(b1, sb, cK1);
        DSA(a0, sb, 0, cK1);
        SBAR(); BARRIER(); WAIT_LGKM0();
        MM16(a0, b1, 0);
        BARRIER(); SBAR();

        // ---- phase 3: kk1, mi 4-7 ----
        DSA(a1, sb, 1, cK1);
        SBAR(); BARRIER(); WAIT_LGKM0();
        MM16(a1, b1, 1);
        BARRIER(); SBAR();
    }

    const float alpha = (OUT_MODE == 3) ? alphap[0] : 0.0f;
    #pragma unroll
    for (int mi = 0; mi < 8; ++mi) {
        #pragma unroll
        for (int ni = 0; ni < 4; ++ni) {
            #pragma unroll
            for (int r = 0; r < 4; ++r) {
                const long row = m0 + wr * 128 + mi * 16 + q * 4 + r;
                const long col = n0 + wc * 64 + ni * 16 + r16;
                float vv = acc[mi][ni][r];
                if (BIAS_MODE == 1) vv += bias[col];
                if (BIAS_MODE == 2) vv += bias[row];
                if (OUT_MODE == 0) {
                    ((__hip_bfloat16*)outp)[(long)z * sC + row * ldC + col] = __float2bfloat16(vv);
                } else if (OUT_MODE == 1) {
                    ((float*)outp)[(long)z * sC + row * ldC + col] = vv;
                } else if (OUT_MODE == 2) {
                    const long addr = (col >> 8) * (long)(kC * kHW) + row * kHW + (col & 255);
                    ((__hip_bfloat16*)outp)[addr] = __float2bfloat16(vv);
                } else {
                    const long addr = (col >> 8) * (long)(kC * kHW) + row * kHW + (col & 255);
                    ((float*)outp)[addr] = alpha * vv + resid[addr];
                }
            }
        }
    }
#undef DSA
#undef DSB
#undef MM16
}

// x (B, C, HW) f32  ->  xT (B*HW, C) bf16
__global__ __launch_bounds__(256) void transpose_x(
    const float* __restrict__ x, __hip_bfloat16* __restrict__ xT)
{
    __shared__ float tile[64][65];
    const int b = blockIdx.z;
    const int c0 = blockIdx.x * 64;
    const int p0 = blockIdx.y * 64;
    const int tj = threadIdx.x & 63;
    const int ti = threadIdx.x >> 6;
    const float* xb = x + ((long)b * kC + c0) * kHW + p0;
    #pragma unroll
    for (int i = 0; i < 16; ++i) {
        const int c = i * 4 + ti;
        tile[c][tj] = xb[(long)c * kHW + tj];
    }
    __syncthreads();
    __hip_bfloat16* o = xT + ((long)(b * kHW + p0)) * kC + c0;
    #pragma unroll
    for (int i = 0; i < 16; ++i) {
        const int p = i * 4 + ti;
        o[(long)p * kC + tj] = __float2bfloat16(tile[tj][p]);
    }
}

__global__ __launch_bounds__(256) void convert_f32_bf16(
    const float* __restrict__ s, __hip_bfloat16* __restrict__ d)
{
    const int i = (blockIdx.x * 256 + threadIdx.x) * 4;
    const float4 f = *reinterpret_cast<const float4*>(s + i);
    d[i + 0] = __float2bfloat16(f.x);
    d[i + 1] = __float2bfloat16(f.y);
    d[i + 2] = __float2bfloat16(f.z);
    d[i + 3] = __float2bfloat16(f.w);
}

__global__ __launch_bounds__(256) void concat_bias(
    const float* __restrict__ bk, const float* __restrict__ bq, float* __restrict__ bc)
{
    const int i = blockIdx.x * 256 + threadIdx.x;  // grid 10*256 = 2560
    bc[i] = (i < 1280) ? bk[i] : bq[i - 1280];
}

// softmax over BATCH axis: scores (B,256,256) f32 -> attn bf16
__global__ __launch_bounds__(256) void softmax_batch(
    const float* __restrict__ scores, __hip_bfloat16* __restrict__ attn)
{
    const int pos = blockIdx.x * 256 + threadIdx.x;
    float m = -3.0e38f, s = 0.0f;
    for (int b = 0; b < kB; ++b) {
        const float v = scores[(long)b * 65536 + pos];
        const float mn = fmaxf(m, v);
        s = s * __expf(m - mn) + __expf(v - mn);
        m = mn;
    }
    const float rinv = 1.0f / s;
    for (int b = 0; b < kB; ++b) {
        const float v = scores[(long)b * 65536 + pos];
        attn[(long)b * 65536 + pos] = __float2bfloat16(__expf(v - m) * rinv);
    }
}

extern "C" void kernel_launch(void* const* d_in, const int* in_sizes, int n_in,
                              void* d_out, int out_size, void* d_ws, size_t ws_size,
                              hipStream_t stream)
{
    const float* x  = (const float*)d_in[0];
    const float* Wk = (const float*)d_in[1];
    const float* bk = (const float*)d_in[2];
    const float* Wq = (const float*)d_in[3];
    const float* bq = (const float*)d_in[4];
    const float* Wv = (const float*)d_in[5];
    const float* bv = (const float*)d_in[6];
    const float* Wr = (const float*)d_in[7];
    const float* br = (const float*)d_in[8];
    const float* al = (const float*)d_in[9];

    char* ws = (char*)d_ws;
    __hip_bfloat16* xT   = (__hip_bfloat16*)(ws);               // 83.9MB; dead after V GEMM
    float*          sc   = (float*)(ws);                        // aliases xT (33.5MB)
    __hip_bfloat16* kqT  = (__hip_bfloat16*)(ws + 83886080L);   // (32768,2560) 167.8MB
    __hip_bfloat16* attn = (__hip_bfloat16*)(ws + 83886080L);   // aliases kqT (16.8MB)
    __hip_bfloat16* att2 = (__hip_bfloat16*)(ws + 100663296L);  // aliases kqT tail (83.9MB)
    __hip_bfloat16* vv   = (__hip_bfloat16*)(ws + 251658240L);  // 83.9MB
    __hip_bfloat16* Wcatb= (__hip_bfloat16*)(ws + 335544320L);  // (2560,1280)
    __hip_bfloat16* Wvb  = Wcatb + 2560 * 1280;
    __hip_bfloat16* Wrb  = Wvb + 1280 * 1280;
    float*          bcat = (float*)(ws + 348651520L);           // 2560 f32

    const int SMEM = 131072;
    hipFuncSetAttribute((const void*)gemm_t<0,1,1>, hipFuncAttributeMaxDynamicSharedMemorySize, SMEM);
    hipFuncSetAttribute((const void*)gemm_t<2,2,0>, hipFuncAttributeMaxDynamicSharedMemorySize, SMEM);
    hipFuncSetAttribute((const void*)gemm_t<1,0,0>, hipFuncAttributeMaxDynamicSharedMemorySize, SMEM);
    hipFuncSetAttribute((const void*)gemm_t<0,0,0>, hipFuncAttributeMaxDynamicSharedMemorySize, SMEM);
    hipFuncSetAttribute((const void*)gemm_t<3,2,0>, hipFuncAttributeMaxDynamicSharedMemorySize, SMEM);

    convert_f32_bf16<<<1600, 256, 0, stream>>>(Wk, Wcatb);
    convert_f32_bf16<<<1600, 256, 0, stream>>>(Wq, Wcatb + 1638400);
    convert_f32_bf16<<<1600, 256, 0, stream>>>(Wv, Wvb);
    convert_f32_bf16<<<1600, 256, 0, stream>>>(Wr, Wrb);
    concat_bias<<<10, 256, 0, stream>>>(bk, bq, bcat);
    transpose_x<<<dim3(20, 4, 128), 256, 0, stream>>>(x, xT);

    // fused K|Q: kqT (32768, 2560) = xT * Wcat^T + bcat[col]; A large -> ORDER=1
    gemm_t<0, 1, 1><<<dim3(1280, 1, 1), 512, SMEM, stream>>>(xT, Wcatb, kqT, bcat, nullptr, nullptr,
        32768, 2560, 1280, 1280, 1280, 0, 0, 0, 2560);
    // v (B,C,HW) = Wv * xT^T + bv[row];  B large -> ORDER=0
    gemm_t<2, 2, 0><<<dim3(640, 1, 1), 512, SMEM, stream>>>(Wvb, xT, vv, bv, nullptr, nullptr,
        1280, 32768, 1280, 1280, 1280, 0, 0, 0, 0);
    // scores (B,256,256) f32 = kT[b] * qT[b]^T
    gemm_t<1, 0, 0><<<dim3(1, 1, 128), 512, SMEM, stream>>>(kqT, kqT + 1280, sc, nullptr, nullptr, nullptr,
        256, 256, 1280, 2560, 2560, 655360, 655360, 65536, 256);
    softmax_batch<<<256, 256, 0, stream>>>(sc, attn);
    // att2 (B,256,1280) = attn[b] * v[b]^T
    gemm_t<0, 0, 0><<<dim3(5, 1, 128), 512, SMEM, stream>>>(attn, vv, att2, nullptr, nullptr, nullptr,
        256, 1280, 256, 256, 256, 65536, 327680, 327680, 1280);
    // out f32 (B,C,HW) = alpha*(Wr*att2^T + br[row]) + x;  B large -> ORDER=0
    gemm_t<3, 2, 0><<<dim3(640, 1, 1), 512, SMEM, stream>>>(Wrb, att2, d_out, br, x, al,
        1280, 32768, 1280, 1280, 1280, 0, 0, 0, 0);
}